// Round 2
// baseline (142.033 us; speedup 1.0000x reference)
//
#include <hip/hip_runtime.h>
#include <math.h>

#define THRESH 0.65f

// Inter-kernel scratch in module-static global memory (d_ws poison-fill is
// unconditional harness behavior — proven R1 — so ws gives no benefit).
// g_sim fully overwritten every iteration before being read.
__device__ float g_sim[32 * 4096];
// Per-map-pair completion counters for the fused last-block epilogue.
// Zero-initialized at module load; reset to 0 by the consuming block each
// iteration (visible to next graph replay via kernel-boundary flush).
__device__ int g_cnt[16];

// Fused kernel: grid (32 px-chunks, 16 map-pairs) x 256 threads.
// Phase 1 (all 512 blocks): identical arithmetic to the verified k_sim.
// Phase 2 (last-finishing block per map-pair): identical arithmetic to the
// verified k_scan_out, run for both maps of the pair. Cross-XCD visibility
// via device-scope release fence + atomicAdd + acquire fence (G16 pattern).
__global__ __launch_bounds__(256) void k_fused(const float* __restrict__ feat,
                                               const float* __restrict__ ref,
                                               float* __restrict__ out) {
    __shared__ float rn0[256], rn1[256], red[256];
    __shared__ float pd0[256], pd1[256], pn[256];
    __shared__ float S[64 * 65];   // sim map, stride 65 (bank pad)
    __shared__ float sc[256];
    __shared__ float wmin[4];
    __shared__ int wmini[4];
    __shared__ int s_last;

    int t = threadIdx.x;
    int m0 = blockIdx.y * 2;

    // ---------------- phase 1: similarity (verified k_sim body) ----------
    float v0 = ref[m0 * 256 + t];
    float v1 = ref[(m0 + 1) * 256 + t];
    red[t] = v0 * v0;
    __syncthreads();
    for (int s = 128; s > 0; s >>= 1) { if (t < s) red[t] += red[t + s]; __syncthreads(); }
    float den0 = sqrtf(red[0]) + 1e-12f;
    __syncthreads();
    red[t] = v1 * v1;
    __syncthreads();
    for (int s = 128; s > 0; s >>= 1) { if (t < s) red[t] += red[t + s]; __syncthreads(); }
    float den1 = sqrtf(red[0]) + 1e-12f;
    rn0[t] = v0 / den0;
    rn1[t] = v1 / den1;
    __syncthreads();

    int half = t >> 7, pxl = t & 127;
    int px = blockIdx.x * 128 + pxl;
    const float* fp = feat + px + half * 128 * 4096;
    const float* r0 = rn0 + half * 128;
    const float* r1 = rn1 + half * 128;
    float d0 = 0.f, d1 = 0.f, nq = 0.f;
    for (int g = 0; g < 8; ++g) {
#pragma unroll
        for (int cc = 0; cc < 16; ++cc) {
            int c = g * 16 + cc;
            float fv = fp[c * 4096];
            d0 += fv * r0[c];
            d1 += fv * r1[c];
            nq += fv * fv;
        }
    }
    pd0[t] = d0; pd1[t] = d1; pn[t] = nq;
    __syncthreads();
    float D0 = pd0[pxl] + pd0[pxl + 128];
    float D1 = pd1[pxl] + pd1[pxl + 128];
    float NQ = pn[pxl] + pn[pxl + 128];
    float den = sqrtf(NQ) + 1e-12f;
    g_sim[(m0 + half) * 4096 + px] = (half ? D1 : D0) / den;

    // ---------------- handoff: device-scope release + last-block elect ---
    __threadfence();               // release this thread's g_sim store
    __syncthreads();               // all 256 stores released
    if (t == 0) {
        int old = atomicAdd(&g_cnt[blockIdx.y], 1);
        s_last = (old == 31);
    }
    __syncthreads();
    if (!s_last) return;
    __threadfence();               // acquire: invalidate stale cached g_sim
    if (t == 0) g_cnt[blockIdx.y] = 0;  // reset for next iteration (race-free:
                                        // all 32 adds ordered before old==31)

    // ---------------- phase 2: scan both maps (verified k_scan_out body) -
    int cy = t >> 4, cx = t & 15;
    int gxs[6];
#pragma unroll
    for (int j = 0; j < 6; ++j) {
        int g = 4 * cx - 1 + j;
        gxs[j] = min(max(g, 0), 63);
    }
    const int   L0[5]  = {0, 8, 24, 40, 56};
    const int   L1[5]  = {7, 23, 39, 55, 63};
    const float WXA[5] = {0.53125f, 0.03125f, 0.03125f, 0.03125f, 0.03125f};
    const float WXB[5] = {0.96875f, 0.96875f, 0.96875f, 0.96875f, 0.46875f};
    const float WCA[5] = {0.46875f, 0.96875f, 0.96875f, 0.96875f, 0.96875f};
    const float WCB[5] = {0.03125f, 0.03125f, 0.03125f, 0.03125f, 0.53125f};

    for (int mm = 0; mm < 2; ++mm) {
        int m = m0 + mm;
        const float* sm = g_sim + m * 4096;
        __syncthreads();           // S reuse safe across mm iterations
        for (int k = 0; k < 16; ++k) {
            int f = t + 256 * k;
            S[(f >> 6) * 65 + (f & 63)] = sm[f];
        }
        __syncthreads();

        float bmax = -1e30f, bmin = 1e30f;
        int bmaxi = 0, bmini = 0;
#pragma unroll
        for (int sy = 0; sy < 5; ++sy) {
#pragma unroll
            for (int e = 0; e < 2; ++e) {
                int r = e ? L1[sy] : L0[sy];      // corner row (cell-local)
                int oy = cy * 64 + r;
                float fy = (oy + 0.5f) * 0.0625f - 0.5f;  // exact dyadic
                float y0f = floorf(fy);
                float wy = fy - y0f, w1y = 1.0f - wy;
                bool ylo = fy < 0.0f, yhi = fy > 63.0f;
                int y0 = (int)y0f;
                const float* P0 = S + min(max(y0, 0), 63) * 65;
                const float* P1 = S + min(max(y0 + 1, 0), 63) * 65;
                float q[6];
#pragma unroll
                for (int j = 0; j < 6; ++j) {
                    float a = P0[gxs[j]], c = P1[gxs[j]];
                    q[j] = ylo ? a : (yhi ? c : w1y * a + wy * c);
                }
#pragma unroll
                for (int s5 = 0; s5 < 5; ++s5) {
                    float q0 = q[s5], q1 = q[s5 + 1];
                    float va, vb;
                    if (cx == 0 && s5 == 0)       { va = q1; vb = q1; }  // fx<0 single tap
                    else if (cx == 15 && s5 == 4) { va = q0; vb = q0; }  // fx>63 single tap
                    else {
                        va = WCA[s5] * q0 + WXA[s5] * q1;
                        vb = WCB[s5] * q0 + WXB[s5] * q1;
                    }
                    float smax, smin; int smaxl, sminl;
                    if (va >= vb) { smax = va; smaxl = L0[s5]; } else { smax = vb; smaxl = L1[s5]; }
                    if (va <= vb) { smin = va; sminl = L0[s5]; } else { smin = vb; sminl = L1[s5]; }
                    if (smax > bmax) { bmax = smax; bmaxi = r * 64 + smaxl; }
                    if (smin < bmin) { bmin = smin; bmini = oy * 1024 + cx * 64 + sminl; }
                }
            }
        }

        // --- threshold + stable descending rank sort (block = whole map) ---
        bool valid = bmax > THRESH;
        float opx = valid ? (float)(cx * 64 + (bmaxi & 63)) : -1.0f;
        float opy = valid ? (float)(cy * 64 + (bmaxi >> 6)) : -1.0f;
        float ops = valid ? bmax : -1.0f;
        sc[t] = ops;
        __syncthreads();
        int rank = 0;
        for (int j = 0; j < 256; ++j) {
            float sj = sc[j];
            rank += (sj > ops || (sj == ops && j < t)) ? 1 : 0;
        }
        float* o = out + m * 768 + rank * 3;
        o[0] = opx; o[1] = opy; o[2] = ops;

        // --- bg argmin: wave reduce + cross-wave merge; lower flat idx wins ---
        for (int off = 32; off > 0; off >>= 1) {
            float mv = __shfl_down(bmin, off);
            int   mj = __shfl_down(bmini, off);
            if (mv < bmin || (mv == bmin && mj < bmini)) { bmin = mv; bmini = mj; }
        }
        if ((t & 63) == 0) { wmin[t >> 6] = bmin; wmini[t >> 6] = bmini; }
        __syncthreads();
        if (t == 0) {
            float bv = wmin[0]; int bi = wmini[0];
            for (int w = 1; w < 4; ++w) {
                if (wmin[w] < bv || (wmin[w] == bv && wmini[w] < bi)) {
                    bv = wmin[w]; bi = wmini[w];
                }
            }
            out[24576 + m * 2 + 0] = (float)(bi % 1024);  // x = col
            out[24576 + m * 2 + 1] = (float)(bi / 1024);  // y = row
        }
    }
}

extern "C" void kernel_launch(void* const* d_in, const int* in_sizes, int n_in,
                              void* d_out, int out_size, void* d_ws, size_t ws_size,
                              hipStream_t stream) {
    const float* feat = (const float*)d_in[0];  // (1,256,64,64)
    const float* ref  = (const float*)d_in[1];  // (32,1,256)
    if (in_sizes[0] == 32 * 256) {  // defensive: swap if order reversed
        feat = (const float*)d_in[1];
        ref  = (const float*)d_in[0];
    }
    float* out = (float*)d_out;
    (void)d_ws; (void)ws_size;  // ws unused; poison-fill is unconditional (R1)

    k_fused<<<dim3(32, 16), 256, 0, stream>>>(feat, ref, out);
}

// Round 3
// 74.619 us; speedup vs baseline: 1.9034x; 1.9034x over previous
//
#include <hip/hip_runtime.h>
#include <math.h>

#define THRESH 0.65f

// Inter-kernel scratch in module-static global memory (d_ws poison-fill is
// unconditional harness behavior — proven R1). g_sim is fully overwritten by
// k_sim before k_scan_out reads it every iteration.
//
// R2 lesson (journal): fusing via last-block epilogue + per-block device-scope
// __threadfence() cost ~140 us on gfx950 (8 non-coherent XCD L2s -> fence =
// serialized L2 writeback). The kernel-boundary sync of the two-launch version
// is the CHEAP synchronization here. dur_us = max(harness reset chain ~74us,
// our chain ~5us) -> two-launch version sits on the harness floor.
__device__ float g_sim[32 * 4096];

// K1: grid (32 px-chunks of 128, 16 map-pairs) x 256 threads.
// Thread t = (channel-half h = t>>7, pxl = t&127). Each feat value is loaded
// once and feeds dot(map0), dot(map1), and nsq -> no redundant norm work.
__global__ __launch_bounds__(256) void k_sim(const float* __restrict__ feat,
                                             const float* __restrict__ ref) {
    __shared__ float rn0[256], rn1[256], red[256];
    __shared__ float pd0[256], pd1[256], pn[256];
    int t = threadIdx.x;
    int m0 = blockIdx.y * 2;

    float v0 = ref[m0 * 256 + t];
    float v1 = ref[(m0 + 1) * 256 + t];
    red[t] = v0 * v0;
    __syncthreads();
    for (int s = 128; s > 0; s >>= 1) { if (t < s) red[t] += red[t + s]; __syncthreads(); }
    float den0 = sqrtf(red[0]) + 1e-12f;
    __syncthreads();
    red[t] = v1 * v1;
    __syncthreads();
    for (int s = 128; s > 0; s >>= 1) { if (t < s) red[t] += red[t + s]; __syncthreads(); }
    float den1 = sqrtf(red[0]) + 1e-12f;
    rn0[t] = v0 / den0;
    rn1[t] = v1 / den1;
    __syncthreads();

    int half = t >> 7, pxl = t & 127;
    int px = blockIdx.x * 128 + pxl;
    const float* fp = feat + px + half * 128 * 4096;
    const float* r0 = rn0 + half * 128;
    const float* r1 = rn1 + half * 128;
    float d0 = 0.f, d1 = 0.f, nq = 0.f;
    for (int g = 0; g < 8; ++g) {
#pragma unroll
        for (int cc = 0; cc < 16; ++cc) {
            int c = g * 16 + cc;
            float fv = fp[c * 4096];
            d0 += fv * r0[c];
            d1 += fv * r1[c];
            nq += fv * fv;
        }
    }
    pd0[t] = d0; pd1[t] = d1; pn[t] = nq;
    __syncthreads();
    float D0 = pd0[pxl] + pd0[pxl + 128];
    float D1 = pd1[pxl] + pd1[pxl + 128];
    float NQ = pn[pxl] + pn[pxl + 128];
    float den = sqrtf(NQ) + 1e-12f;
    g_sim[(m0 + half) * 4096 + px] = (half ? D1 : D0) / den;
}

// K2: 32 blocks (one per map) x 256 threads (thread = cell).
// 2D segment-corner evaluation: v is bilinear within each (y-seg x x-seg)
// rectangle (exact dyadic weights), so extrema are at the 4 corners. Corners
// are evaluated with the reference's own per-sample formula (y-combine then
// x-combine, single-tap clamp passthrough). Candidates visited in global
// row-major order with strict compares -> first-occurrence tie semantics.
// Sort + bg argmin are block-local (whole map in one block).
__global__ __launch_bounds__(256) void k_scan_out(float* __restrict__ out) {
    __shared__ float S[64 * 65];   // sim map, stride 65 (bank pad)
    __shared__ float sc[256];
    __shared__ float wmin[4];
    __shared__ int wmini[4];

    int m = blockIdx.x, t = threadIdx.x;
    const float* sm = g_sim + m * 4096;
    for (int k = 0; k < 16; ++k) {
        int f = t + 256 * k;
        S[(f >> 6) * 65 + (f & 63)] = sm[f];
    }
    __syncthreads();

    int cy = t >> 4, cx = t & 15;
    int gxs[6];
#pragma unroll
    for (int j = 0; j < 6; ++j) {
        int g = 4 * cx - 1 + j;
        gxs[j] = min(max(g, 0), 63);
    }
    const int   L0[5]  = {0, 8, 24, 40, 56};
    const int   L1[5]  = {7, 23, 39, 55, 63};
    const float WXA[5] = {0.53125f, 0.03125f, 0.03125f, 0.03125f, 0.03125f};
    const float WXB[5] = {0.96875f, 0.96875f, 0.96875f, 0.96875f, 0.46875f};
    const float WCA[5] = {0.46875f, 0.96875f, 0.96875f, 0.96875f, 0.96875f};
    const float WCB[5] = {0.03125f, 0.03125f, 0.03125f, 0.03125f, 0.53125f};

    float bmax = -1e30f, bmin = 1e30f;
    int bmaxi = 0, bmini = 0;
#pragma unroll
    for (int sy = 0; sy < 5; ++sy) {
#pragma unroll
        for (int e = 0; e < 2; ++e) {
            int r = e ? L1[sy] : L0[sy];      // corner row (cell-local)
            int oy = cy * 64 + r;
            float fy = (oy + 0.5f) * 0.0625f - 0.5f;  // exact dyadic
            float y0f = floorf(fy);
            float wy = fy - y0f, w1y = 1.0f - wy;
            bool ylo = fy < 0.0f, yhi = fy > 63.0f;
            int y0 = (int)y0f;
            const float* P0 = S + min(max(y0, 0), 63) * 65;
            const float* P1 = S + min(max(y0 + 1, 0), 63) * 65;
            float q[6];
#pragma unroll
            for (int j = 0; j < 6; ++j) {
                float a = P0[gxs[j]], c = P1[gxs[j]];
                q[j] = ylo ? a : (yhi ? c : w1y * a + wy * c);
            }
#pragma unroll
            for (int s5 = 0; s5 < 5; ++s5) {
                float q0 = q[s5], q1 = q[s5 + 1];
                float va, vb;
                if (cx == 0 && s5 == 0)       { va = q1; vb = q1; }  // fx<0 single tap
                else if (cx == 15 && s5 == 4) { va = q0; vb = q0; }  // fx>63 single tap
                else {
                    va = WCA[s5] * q0 + WXA[s5] * q1;
                    vb = WCB[s5] * q0 + WXB[s5] * q1;
                }
                float smax, smin; int smaxl, sminl;
                if (va >= vb) { smax = va; smaxl = L0[s5]; } else { smax = vb; smaxl = L1[s5]; }
                if (va <= vb) { smin = va; sminl = L0[s5]; } else { smin = vb; sminl = L1[s5]; }
                if (smax > bmax) { bmax = smax; bmaxi = r * 64 + smaxl; }
                if (smin < bmin) { bmin = smin; bmini = oy * 1024 + cx * 64 + sminl; }
            }
        }
    }

    // --- threshold + stable descending rank sort (block = whole map) ---
    bool valid = bmax > THRESH;
    float px = valid ? (float)(cx * 64 + (bmaxi & 63)) : -1.0f;
    float py = valid ? (float)(cy * 64 + (bmaxi >> 6)) : -1.0f;
    float ps = valid ? bmax : -1.0f;
    sc[t] = ps;
    __syncthreads();
    int rank = 0;
    for (int j = 0; j < 256; ++j) {
        float sj = sc[j];
        rank += (sj > ps || (sj == ps && j < t)) ? 1 : 0;
    }
    float* o = out + m * 768 + rank * 3;
    o[0] = px; o[1] = py; o[2] = ps;

    // --- bg argmin: wave reduce + cross-wave merge; lower flat idx wins ties ---
    for (int off = 32; off > 0; off >>= 1) {
        float mv = __shfl_down(bmin, off);
        int   mj = __shfl_down(bmini, off);
        if (mv < bmin || (mv == bmin && mj < bmini)) { bmin = mv; bmini = mj; }
    }
    if ((t & 63) == 0) { wmin[t >> 6] = bmin; wmini[t >> 6] = bmini; }
    __syncthreads();
    if (t == 0) {
        float bv = wmin[0]; int bi = wmini[0];
        for (int w = 1; w < 4; ++w) {
            if (wmin[w] < bv || (wmin[w] == bv && wmini[w] < bi)) {
                bv = wmin[w]; bi = wmini[w];
            }
        }
        out[24576 + m * 2 + 0] = (float)(bi % 1024);  // x = col
        out[24576 + m * 2 + 1] = (float)(bi / 1024);  // y = row
    }
}

extern "C" void kernel_launch(void* const* d_in, const int* in_sizes, int n_in,
                              void* d_out, int out_size, void* d_ws, size_t ws_size,
                              hipStream_t stream) {
    const float* feat = (const float*)d_in[0];  // (1,256,64,64)
    const float* ref  = (const float*)d_in[1];  // (32,1,256)
    if (in_sizes[0] == 32 * 256) {  // defensive: swap if order reversed
        feat = (const float*)d_in[1];
        ref  = (const float*)d_in[0];
    }
    float* out = (float*)d_out;
    (void)d_ws; (void)ws_size;  // ws unused; poison-fill is unconditional (R1)

    k_sim<<<dim3(32, 16), 256, 0, stream>>>(feat, ref);
    k_scan_out<<<32, 256, 0, stream>>>(out);
}